// Round 1
// baseline (90.470 us; speedup 1.0000x reference)
//
#include <hip/hip_runtime.h>
#include <hip/hip_fp16.h>

#define NQ   13
#define DIM  8192
#define PI_F 3.14159265358979323846f
#define NT   512     // 8 waves/block; grid 512 -> 2 blocks/CU -> 4 waves/SIMD
#define NAMP 16      // amplitudes per thread (4-bit register window)

// Global LDS layout: slot L(i) = i + 4*(i>>5) + 16*(i>>8)  (half2 slots).
// The +16*(i>>8) term spreads W1/W2 lanes over all 32 banks (4-bit windows
// only span 16 banks under the old +4-per-32 padding -> 4-way conflict).
// All four patterns verified 2-way-or-better (free per m136).
#define NSLOT 9712   // L(8191) = 9707, rounded up to a 16B multiple

// Pattern windows (i-bit positions owned by the 4-bit register index j):
//  W0: {0,1,2,3}    i = (t<<4)|j                      contiguous 16 -> 4x b128
//  W1: {4,5,6,7}    i = ((t>>4)<<8)|(j<<4)|(t&15)     scalar b32
//  W2: {8,9,10,11}  i = ((t>>8)<<12)|(j<<8)|(t&255)   scalar b32
//  W3: {0,1,2,12}   i = ((j>>3)<<12)|(t<<3)|(j&7)     2 runs of 8 -> 4x b128
// W0 and W1 both pin i bits {10,11,12} = wave id -> waveFence transition.
__device__ __forceinline__ int base0(int t) { return 16 * t + 4 * (t >> 1) + 16 * (t >> 4); }
__device__ __forceinline__ int slot1f(int t, int j) {
  return 304 * (t >> 4) + (t & 15) + 16 * j + 4 * (j >> 1);
}
__device__ __forceinline__ int slot2f(int t, int j) {
  return 4864 * (t >> 8) + (t & 255) + 4 * ((t >> 5) & 7) + 304 * j;
}
__device__ __forceinline__ int base3(int t) { return 8 * t + 4 * (t >> 2) + 16 * (t >> 5); }
// second W3 run (i bit12 = 1) lives at base3(t) + 4864

union F4H { float4 f; __half2 h[4]; };

__device__ __forceinline__ void rsincos(float x, float* s, float* c) {
  const float INV2PI = 0.15915494309189535f;
  const float TWOPI  = 6.283185307179586f;
  float r = x * INV2PI;
  r -= rintf(r);
  float ang = r * TWOPI;
  *s = __sinf(ang);
  *c = __cosf(ang);
}

// wave-local "barrier" (W0<->W1 both pin i-bits 10,11,12 to the wave id)
__device__ __forceinline__ void waveFence() {
  __builtin_amdgcn_wave_barrier();
  __threadfence_block();
  __builtin_amdgcn_wave_barrier();
}

// ---- fp32 helpers
__device__ __forceinline__ float2 f2fma(float s, float2 a, float2 b) {
  return make_float2(fmaf(s, a.x, b.x), fmaf(s, a.y, b.y));
}
__device__ __forceinline__ float2 f2add(float2 a, float2 b) {
  return make_float2(a.x + b.x, a.y + b.y);
}
__device__ __forceinline__ float2 f2sub(float2 a, float2 b) {
  return make_float2(a.x - b.x, a.y - b.y);
}
__device__ __forceinline__ float2 cphase(float2 v, float cs, float sn) {
  return make_float2(fmaf(cs, v.x, -sn * v.y), fmaf(cs, v.y, sn * v.x));
}
__device__ __forceinline__ float2 cmul(float2 a, float2 b) {
  return make_float2(fmaf(a.x, b.x, -a.y * b.y), fmaf(a.x, b.y, a.y * b.x));
}

// ---- LDS access, W0 (4x b128)
__device__ __forceinline__ void loadA0f(const __half2* __restrict__ sAmp, int t, float2* amp) {
  const __half2* p = sAmp + base0(t);
  #pragma unroll
  for (int k = 0; k < 4; k++) {
    F4H u; u.f = *reinterpret_cast<const float4*>(p + 4 * k);
    #pragma unroll
    for (int c = 0; c < 4; c++) amp[4 * k + c] = __half22float2(u.h[c]);
  }
}
__device__ __forceinline__ void storeA0f(__half2* __restrict__ sAmp, int t, const float2* amp) {
  __half2* p = sAmp + base0(t);
  #pragma unroll
  for (int k = 0; k < 4; k++) {
    F4H u;
    #pragma unroll
    for (int c = 0; c < 4; c++) u.h[c] = __float22half2_rn(amp[4 * k + c]);
    *reinterpret_cast<float4*>(p + 4 * k) = u.f;
  }
}

// ---- LDS access, W3 (2 runs of 8 -> 4x b128)
__device__ __forceinline__ void loadA3f(const __half2* __restrict__ sAmp, int t, float2* amp) {
  const __half2* p = sAmp + base3(t);
  #pragma unroll
  for (int k = 0; k < 2; k++) {
    F4H u; u.f = *reinterpret_cast<const float4*>(p + 4 * k);
    #pragma unroll
    for (int c = 0; c < 4; c++) amp[4 * k + c] = __half22float2(u.h[c]);
  }
  p += 4864;
  #pragma unroll
  for (int k = 0; k < 2; k++) {
    F4H u; u.f = *reinterpret_cast<const float4*>(p + 4 * k);
    #pragma unroll
    for (int c = 0; c < 4; c++) amp[8 + 4 * k + c] = __half22float2(u.h[c]);
  }
}
__device__ __forceinline__ void storeA3f(__half2* __restrict__ sAmp, int t, const float2* amp) {
  __half2* p = sAmp + base3(t);
  #pragma unroll
  for (int k = 0; k < 2; k++) {
    F4H u;
    #pragma unroll
    for (int c = 0; c < 4; c++) u.h[c] = __float22half2_rn(amp[4 * k + c]);
    *reinterpret_cast<float4*>(p + 4 * k) = u.f;
  }
  p += 4864;
  #pragma unroll
  for (int k = 0; k < 2; k++) {
    F4H u;
    #pragma unroll
    for (int c = 0; c < 4; c++) u.h[c] = __float22half2_rn(amp[8 + 4 * k + c]);
    *reinterpret_cast<float4*>(p + 4 * k) = u.f;
  }
}

// ---- LDS access, W1 / W2 (scalar b32)
__device__ __forceinline__ void loadA1h(const __half2* __restrict__ sAmp, int t, __half2* amp) {
  #pragma unroll
  for (int j = 0; j < NAMP; j++) amp[j] = sAmp[slot1f(t, j)];
}
__device__ __forceinline__ void storeA1h(__half2* __restrict__ sAmp, int t, const __half2* amp) {
  #pragma unroll
  for (int j = 0; j < NAMP; j++) sAmp[slot1f(t, j)] = amp[j];
}
__device__ __forceinline__ void loadA2h(const __half2* __restrict__ sAmp, int t, __half2* amp) {
  #pragma unroll
  for (int j = 0; j < NAMP; j++) amp[j] = sAmp[slot2f(t, j)];
}
__device__ __forceinline__ void storeA2h(__half2* __restrict__ sAmp, int t, const __half2* amp) {
  #pragma unroll
  for (int j = 0; j < NAMP; j++) sAmp[slot2f(t, j)] = amp[j];
}
__device__ __forceinline__ void loadA2f(const __half2* __restrict__ sAmp, int t, float2* amp) {
  #pragma unroll
  for (int j = 0; j < NAMP; j++) amp[j] = __half22float2(sAmp[slot2f(t, j)]);
}
__device__ __forceinline__ void storeA2f(__half2* __restrict__ sAmp, int t, const float2* amp) {
  #pragma unroll
  for (int j = 0; j < NAMP; j++) sAmp[slot2f(t, j)] = __float22half2_rn(amp[j]);
}

// ---- fp32 gate math
template<int KB>
__device__ __forceinline__ void fwht_bit(float2* amp) {
  #pragma unroll
  for (int j = 0; j < NAMP; j++) if (!(j & (1 << KB))) {
    int j1 = j | (1 << KB);
    float2 a0 = amp[j], a1 = amp[j1];
    amp[j]  = f2add(a0, a1);
    amp[j1] = f2sub(a0, a1);
  }
}
template<int KB>
__device__ __forceinline__ void applyRy(float2* amp, float ta, float sa) {
  #pragma unroll
  for (int j = 0; j < NAMP; j++) if (!(j & (1 << KB))) {
    int j1 = j | (1 << KB);
    amp[j]  = f2fma(-ta, amp[j1], amp[j]);
    amp[j1] = f2fma( sa, amp[j],  amp[j1]);
    amp[j]  = f2fma(-ta, amp[j1], amp[j]);
  }
}

// ---- fp16 packed gate math
template<int KB>
__device__ __forceinline__ void fwht_bitH(__half2* amp) {
  #pragma unroll
  for (int j = 0; j < NAMP; j++) if (!(j & (1 << KB))) {
    int j1 = j | (1 << KB);
    __half2 a0 = amp[j], a1 = amp[j1];
    amp[j]  = __hadd2(a0, a1);
    amp[j1] = __hsub2(a0, a1);
  }
}
template<int KB>
__device__ __forceinline__ void applyRyH(__half2* amp, __half2 nta, __half2 sa) {
  #pragma unroll
  for (int j = 0; j < NAMP; j++) if (!(j & (1 << KB))) {
    int j1 = j | (1 << KB);
    amp[j]  = __hfma2(nta, amp[j1], amp[j]);
    amp[j1] = __hfma2(sa,  amp[j],  amp[j1]);
    amp[j]  = __hfma2(nta, amp[j1], amp[j]);
  }
}

// phase tree over a 4-bit window.
// PAT 0: base from i bits 4..12 (t bits 0..8), window {0,1,2,3}
// PAT 3: base from i bits 3..11 (t bits 0..8), window {0,1,2,12}
template<int PAT>
__device__ __forceinline__ void buildTree(const float* __restrict__ w, float bias,
                                          int t, float* s) {
  float base = bias;
  constexpr int B0 = (PAT == 0) ? 4 : 3;
  #pragma unroll
  for (int k = 0; k < 9; k++) base += ((t >> k) & 1) ? w[B0 + k] : 0.0f;
  constexpr int P[4] = { 0, 1, 2, (PAT == 0) ? 3 : 12 };
  s[0] = base;
  #pragma unroll
  for (int k = 0; k < 4; k++) {
    float wp = w[P[k]];
    #pragma unroll
    for (int m = 0; m < (1 << k); m++) s[m | (1 << k)] = s[m] + wp;
  }
}

// psi *= exp(i*phi(i)), phi = u + 0.5*(v^2 - A2); INIT writes unit phase
template<int PAT, bool INIT>
__device__ __forceinline__ void featureDiag(float2* amp,
                                            const float* __restrict__ wX,
                                            const float* __restrict__ wA,
                                            const float* __restrict__ cons, int t) {
  float u[NAMP], v[NAMP];
  buildTree<PAT>(wX, cons[0], t, u);
  buildTree<PAT>(wA, cons[1], t, v);
  float A2 = cons[2];
  #pragma unroll
  for (int j = 0; j < NAMP; j++) {
    float phi = u[j] + 0.5f * (v[j] * v[j] - A2);
    float sn, cs; rsincos(phi, &sn, &cs);
    if constexpr (INIT) amp[j] = make_float2(cs, sn);
    else                amp[j] = cphase(amp[j], cs, sn);
  }
}

// psi *= ENT(i)*exp(i*rho(i)) on W0 (window {0,1,2,3}); rho = Rz layer phase.
// base: i bits 4..12 from t; complex product tree over window bits 0..3.
__device__ __forceinline__ void applyDiagW0(float2* amp,
                                            const float* __restrict__ wb,
                                            const float* __restrict__ eR,
                                            const float* __restrict__ eI,
                                            float bias, int t) {
  float base = bias;
  #pragma unroll
  for (int k = 0; k < 9; k++) base += ((t >> k) & 1) ? wb[4 + k] : 0.0f;
  float2 c[16];
  { float sn, cs; rsincos(base, &sn, &cs); c[0] = make_float2(cs, sn); }
  #pragma unroll
  for (int k = 0; k < 4; k++) {
    float2 e = make_float2(eR[k], eI[k]);
    #pragma unroll
    for (int m = 0; m < (1 << k); m++) c[m | (1 << k)] = cmul(c[m], e);
  }
  #pragma unroll
  for (int j = 0; j < 16; j++) {
    int i = (t << 4) | j;
    float sgn = (__popc(i & (i >> 1)) & 1) ? -1.0f : 1.0f;
    amp[j] = cphase(amp[j], c[j].x * sgn, c[j].y * sgn);
  }
}

// (512,4): 8 waves/block, cap VGPR<=128 so 2 blocks/CU = 4 waves/SIMD resident.
__global__ __launch_bounds__(NT, 4) void qc_kernel(
    const float* __restrict__ xin,
    const float* __restrict__ thin,
    const float* __restrict__ bin,
    float* __restrict__ out) {
  __shared__ alignas(16) __half2 sAmp[NSLOT];
  __shared__ float gTA[65], gSA[65];      // fp32 shear coeffs, indexed l*13+qubit
  __shared__ __half2 hNTA[65], hSA[65];   // packed (-ta,-ta),(sa,sa), l*13+qubit
  __shared__ float gBbit[65];             // Rz b by [l*13 + bitpos], bitpos = 12-q
  __shared__ float eBr[65], eBi[65];      // cos(b), sin(b) by [l*13 + bitpos]
  __shared__ float wX[13], wA[13];        // -2x, -2a by bitpos
  __shared__ float cons[8];               // 0:X 1:A 2:A2 3..7:-0.5*sum b_l
  __shared__ float red[NT / 64];

  const int t = threadIdx.x;
  const int b = blockIdx.x;

  if (t < NQ) {
    float xq = xin[b * NQ + t];
    float aq = PI_F - xq;
    wX[12 - t] = -2.0f * xq;
    wA[12 - t] = -2.0f * aq;
  }
  if (t < 65) {
    float av = thin[2 * t];
    float bv = thin[2 * t + 1];
    float ca = cosf(0.5f * av);
    float sa = sinf(0.5f * av);
    float ta = sa / (1.0f + ca);
    gTA[t] = ta;
    gSA[t] = sa;
    hNTA[t] = __float2half2_rn(-ta);
    hSA[t]  = __float2half2_rn(sa);
    int l = t / NQ, q = t % NQ;
    int s = l * NQ + (12 - q);
    gBbit[s] = bv;
    eBr[s] = cosf(bv);
    eBi[s] = sinf(bv);
  }
  __syncthreads();
  if (t == 0) {
    float X = 0.f, A = 0.f, A2 = 0.f;
    for (int p = 0; p < NQ; p++) {
      float xq = -0.5f * wX[p], aq = -0.5f * wA[p];
      X += xq; A += aq; A2 += aq * aq;
    }
    cons[0] = X; cons[1] = A; cons[2] = A2;
    for (int l = 0; l < 5; l++) {
      float s = 0.f;
      for (int p = 0; p < NQ; p++) s += gBbit[l * NQ + p];
      cons[3 + l] = -0.5f * s;
    }
  }
  __syncthreads();

  // ---- P0 (W0, fp32): init psi = exp(i*phi); FWHT bits 0..3
  {
    float2 amp[NAMP];
    featureDiag<0, true>(amp, wX, wA, cons, t);
    fwht_bit<0>(amp); fwht_bit<1>(amp); fwht_bit<2>(amp); fwht_bit<3>(amp);
    storeA0f(sAmp, t, amp);
  }
  waveFence();   // W0->W1 wave-private

  // ---- P1 (W1, fp16): FWHT bits 4..7
  {
    __half2 amp[NAMP];
    loadA1h(sAmp, t, amp);
    fwht_bitH<0>(amp); fwht_bitH<1>(amp); fwht_bitH<2>(amp); fwht_bitH<3>(amp);
    storeA1h(sAmp, t, amp);
  }
  __syncthreads();

  // ---- P2 (W2, fp32): FWHT bits 8..11
  {
    float2 amp[NAMP];
    loadA2f(sAmp, t, amp);
    fwht_bit<0>(amp); fwht_bit<1>(amp); fwht_bit<2>(amp); fwht_bit<3>(amp);
    storeA2f(sAmp, t, amp);
  }
  __syncthreads();

  // ---- P3 (W3, fp32): FWHT bit 12 (reg bit 3); 2nd feature diag;
  //      L0 gates on window {0,1,2,12} -> qubits 12,11,10,0
  {
    float2 amp[NAMP];
    loadA3f(sAmp, t, amp);
    fwht_bit<3>(amp);
    featureDiag<3, false>(amp, wX, wA, cons, t);
    applyRy<0>(amp, gTA[12], gSA[12]);
    applyRy<1>(amp, gTA[11], gSA[11]);
    applyRy<2>(amp, gTA[10], gSA[10]);
    applyRy<3>(amp, gTA[0],  gSA[0]);
    storeA3f(sAmp, t, amp);
  }
  __syncthreads();

  // ---- Layers: W3 fp32 (q12,q11,q10,q0) -> W2 fp16 (q4..q1) ->
  //      W1 fp16 (q8..q5) -> [waveFence] W0 fp32 (q9 + diag_l / readout)
  float acc = 0.0f;
  for (int l = 0; l < 5; l++) {
    const int g = l * NQ;
    if (l > 0) {
      // W3 (fp32): reg bits 0,1,2 -> qubits 12,11,10; reg bit 3 -> qubit 0
      float2 amp[NAMP];
      loadA3f(sAmp, t, amp);
      applyRy<0>(amp, gTA[g + 12], gSA[g + 12]);
      applyRy<1>(amp, gTA[g + 11], gSA[g + 11]);
      applyRy<2>(amp, gTA[g + 10], gSA[g + 10]);
      applyRy<3>(amp, gTA[g + 0],  gSA[g + 0]);
      storeA3f(sAmp, t, amp);
      __syncthreads();
    }
    // W2 (fp16): reg bits 0..3 -> qubits 4,3,2,1
    {
      __half2 amp[NAMP];
      loadA2h(sAmp, t, amp);
      applyRyH<0>(amp, hNTA[g + 4], hSA[g + 4]);
      applyRyH<1>(amp, hNTA[g + 3], hSA[g + 3]);
      applyRyH<2>(amp, hNTA[g + 2], hSA[g + 2]);
      applyRyH<3>(amp, hNTA[g + 1], hSA[g + 1]);
      storeA2h(sAmp, t, amp);
    }
    __syncthreads();
    // W1 (fp16): reg bits 0..3 -> qubits 8,7,6,5
    {
      __half2 amp[NAMP];
      loadA1h(sAmp, t, amp);
      applyRyH<0>(amp, hNTA[g + 8], hSA[g + 8]);
      applyRyH<1>(amp, hNTA[g + 7], hSA[g + 7]);
      applyRyH<2>(amp, hNTA[g + 6], hSA[g + 6]);
      applyRyH<3>(amp, hNTA[g + 5], hSA[g + 5]);
      storeA1h(sAmp, t, amp);
    }
    waveFence();   // W1->W0 wave-private
    // W0 (fp32): reg bit 3 -> qubit 9; then diag_l (l<4) or readout (l=4)
    {
      float2 amp[NAMP];
      loadA0f(sAmp, t, amp);
      applyRy<3>(amp, gTA[g + 9], gSA[g + 9]);
      if (l < 4) {
        applyDiagW0(amp, gBbit + g, eBr + g, eBi + g, cons[3 + l], t);
        storeA0f(sAmp, t, amp);
      } else {
        // all L4 non-diagonal gates applied; trailing Rz invisible in |amp|^2
        int pt = __popc(t) & 1;
        #pragma unroll
        for (int j = 0; j < NAMP; j++) {
          float p2 = fmaf(amp[j].x, amp[j].x, amp[j].y * amp[j].y);
          acc += ((pt + __popc(j)) & 1) ? -p2 : p2;
        }
      }
    }
    if (l < 4) __syncthreads();
  }

  // block reduction (raw scale 2^26)
  #pragma unroll
  for (int off = 32; off > 0; off >>= 1) acc += __shfl_down(acc, off, 64);
  if ((t & 63) == 0) red[t >> 6] = acc;
  __syncthreads();
  if (t == 0) {
    float total = 0.f;
    #pragma unroll
    for (int w = 0; w < NT / 64; w++) total += red[w];
    float logit = total * (1.0f / 67108864.0f) + bin[0];
    out[b * 2 + 0] = -logit;
    out[b * 2 + 1] = logit;
  }
}

extern "C" void kernel_launch(void* const* d_in, const int* in_sizes, int n_in,
                              void* d_out, int out_size, void* d_ws, size_t ws_size,
                              hipStream_t stream) {
  const float* x  = (const float*)d_in[0];
  const float* th = (const float*)d_in[1];
  const float* bi = (const float*)d_in[2];
  float* out = (float*)d_out;
  int B = in_sizes[0] / NQ;   // 512
  qc_kernel<<<B, NT, 0, stream>>>(x, th, bi, out);
}